// Round 1
// baseline (1137.681 us; speedup 1.0000x reference)
//
#include <hip/hip_runtime.h>

#define NB 16
#define NT 12
#define NN 30000
#define NF 4
#define NE 960000
#define ORDER 7
#define GOUT 18
#define OUT_CH 126
#define MLP_H 64
#define HOR 12
#define NOUT 4
#define EMB 32

__device__ __forceinline__ float silu_f(float x) {
    return x / (1.0f + __expf(-x));
}

// ---- graph preprocessing -------------------------------------------------

__global__ __launch_bounds__(256) void k_deg_cnt(
    const int* __restrict__ ei, const float* __restrict__ ew,
    float* degF, float* degB, int* cntF, int* cntB)
{
    int e = blockIdx.x * 256 + threadIdx.x;
    if (e >= NE) return;
    int s = ei[e], d = ei[NE + e];
    float w = ew[e];
    atomicAdd(&degF[d], w);
    atomicAdd(&degB[s], w);
    atomicAdd(&cntF[d], 1);
    atomicAdd(&cntB[s], 1);
}

__global__ __launch_bounds__(1024) void k_scan(
    const int* __restrict__ cntF, const int* __restrict__ cntB,
    int* __restrict__ rowF, int* __restrict__ rowB)
{
    const int* cnt = (blockIdx.x == 0) ? cntF : cntB;
    int* row = (blockIdx.x == 0) ? rowF : rowB;
    __shared__ int part[1024];
    int t = threadIdx.x;
    const int CH = (NN + 1023) / 1024;
    int lo = t * CH, hi = min(lo + CH, NN);
    int s = 0;
    for (int i = lo; i < hi; ++i) s += cnt[i];
    part[t] = s;
    __syncthreads();
    if (t == 0) {
        int run = 0;
        for (int i = 0; i < 1024; ++i) { int v = part[i]; part[i] = run; run += v; }
        row[NN] = run;
    }
    __syncthreads();
    int run = part[t];
    for (int i = lo; i < hi; ++i) { row[i] = run; run += cnt[i]; }
}

__global__ __launch_bounds__(256) void k_scatter(
    const int* __restrict__ ei, const float* __restrict__ ew,
    const float* __restrict__ degF, const float* __restrict__ degB,
    const int* __restrict__ rowF, const int* __restrict__ rowB,
    int* curF, int* curB,
    int* __restrict__ csrSF, float* __restrict__ csrWF,
    int* __restrict__ csrSB, float* __restrict__ csrWB)
{
    int e = blockIdx.x * 256 + threadIdx.x;
    if (e >= NE) return;
    int s = ei[e], d = ei[NE + e];
    float w = ew[e];
    int pF = rowF[d] + atomicAdd(&curF[d], 1);
    csrSF[pF] = s;
    csrWF[pF] = w / fmaxf(degF[d], 1e-8f);
    int pB = rowB[s] + atomicAdd(&curB[s], 1);
    csrSB[pB] = d;
    csrWB[pB] = w / fmaxf(degB[s], 1e-8f);
}

// ---- xt transpose: x[b, T-1, n, f] -> xt[n, b, f] ------------------------

__global__ __launch_bounds__(256) void k_transpose(
    const float* __restrict__ x, float* __restrict__ xt)
{
    int t = blockIdx.x * 256 + threadIdx.x;   // n*64 + b*4 + f
    if (t >= NN * 64) return;
    int n = t >> 6, l = t & 63;
    int b = l >> 2, f = l & 3;
    xt[t] = x[((((size_t)b * NT) + (NT - 1)) * NN + n) * NF + f];
}

// ---- node_part[n, c] = node_emb[n] @ emb_w + emb_b -----------------------

__global__ __launch_bounds__(128) void k_node_part(
    const float* __restrict__ emb, const float* __restrict__ ewt,
    const float* __restrict__ eb, float* __restrict__ np_)
{
    int n = blockIdx.x, c = threadIdx.x;
    if (c >= OUT_CH) return;
    float a = eb[c];
    #pragma unroll
    for (int k = 0; k < EMB; ++k)
        a += emb[n * EMB + k] * ewt[k * OUT_CH + c];
    np_[n * OUT_CH + c] = a;
}

// ---- one hop level (fwd + bwd halves), gather over CSR -------------------

__global__ __launch_bounds__(256) void k_hop(
    const float* __restrict__ inF, float* __restrict__ outF,
    const int* __restrict__ srcF, const float* __restrict__ wF, const int* __restrict__ rowF,
    const float* __restrict__ inB, float* __restrict__ outB,
    const int* __restrict__ srcB, const float* __restrict__ wB, const int* __restrict__ rowB)
{
    int lane = threadIdx.x & 63;
    int node = blockIdx.x * 4 + (threadIdx.x >> 6);
    if (node >= NN) return;
    const float* in; float* out; const int* cs; const float* cw; const int* row;
    if (blockIdx.y == 0) { in = inF; out = outF; cs = srcF; cw = wF; row = rowF; }
    else                 { in = inB; out = outB; cs = srcB; cw = wB; row = rowB; }
    int beg = row[node], end = row[node + 1];
    float acc = 0.f;
    int j = beg;
    if (j < end) {
        int s = cs[j]; float w = cw[j];
        for (; j + 1 < end; ++j) {
            int s2 = cs[j + 1]; float w2 = cw[j + 1];
            acc += w * in[s * 64 + lane];
            s = s2; w = w2;
        }
        acc += w * in[s * 64 + lane];
    }
    out[node * 64 + lane] = acc;
}

// ---- fused conv + silu + node_part + mlp + silu + readout ----------------
// block: 256 threads, 2 nodes (32 rows = 2 nodes x 16 batches)

__global__ __launch_bounds__(256) void k_fused(
    const float* __restrict__ xt, const float* __restrict__ h1,
    const float* __restrict__ h2, const float* __restrict__ h3,
    const float* __restrict__ h4, const float* __restrict__ h5,
    const float* __restrict__ h6,
    const float* __restrict__ conv_w, const float* __restrict__ conv_b,
    const float* __restrict__ np_, const float* __restrict__ mlp_w,
    const float* __restrict__ mlp_b, const float* __restrict__ ro_w,
    const float* __restrict__ ro_b, float* __restrict__ out)
{
    __shared__ __align__(16) float Wm[OUT_CH * 64];   // reused: C1t (2048) + roL (3072)
    __shared__ __align__(16) float Ht[OUT_CH * 32];
    __shared__ float hopsL[7 * 128];
    __shared__ float convwL[ORDER * NF * GOUT];
    __shared__ float npL[2 * OUT_CH];
    __shared__ float cbL[OUT_CH];
    __shared__ float mbL[MLP_H];
    __shared__ float rbL[HOR * NOUT];

    int t = threadIdx.x;
    int n0 = blockIdx.x * 2;

    for (int i = t; i < OUT_CH * 64; i += 256) Wm[i] = mlp_w[i];
    for (int i = t; i < ORDER * NF * GOUT; i += 256) convwL[i] = conv_w[i];
    for (int i = t; i < 2 * OUT_CH; i += 256) npL[i] = np_[(size_t)n0 * OUT_CH + i];
    if (t < OUT_CH) cbL[t] = conv_b[t];
    if (t < MLP_H) mbL[t] = mlp_b[t];
    if (t < HOR * NOUT) rbL[t] = ro_b[t];
    {
        const float* bufs[7] = {xt, h1, h2, h3, h4, h5, h6};
        if (t < 128) {
            #pragma unroll
            for (int g = 0; g < 7; ++g)
                hopsL[g * 128 + t] = bufs[g][n0 * 64 + t];
        }
    }
    __syncthreads();

    // Stage 1: Ht[c][r] = silu(conv(hops) + conv_b) + node_part
    {
        int r = t & 31, cq = t >> 5;
        int nl = r >> 4;
        for (int c = cq; c < OUT_CH; c += 8) {
            int g = c / GOUT, q = c - g * GOUT;
            float a = cbL[c];
            #pragma unroll
            for (int i = 0; i < NF; ++i)
                a += hopsL[g * 128 + r * 4 + i] * convwL[(g * 4 + i) * GOUT + q];
            Ht[c * 32 + r] = silu_f(a) + npL[nl * OUT_CH + c];
        }
    }
    __syncthreads();

    // Stage 2: (32 x 126) @ (126 x 64), 2x4 register tile per thread
    int tr = t & 15, tc = t >> 4;
    int r0 = tr * 2, j0 = tc * 4;
    float acc[2][4];
    #pragma unroll
    for (int jj = 0; jj < 4; ++jj) { acc[0][jj] = mbL[j0 + jj]; acc[1][jj] = mbL[j0 + jj]; }
    for (int c = 0; c < OUT_CH; ++c) {
        float2 hv = *(const float2*)&Ht[c * 32 + r0];
        float4 wv = *(const float4*)&Wm[c * 64 + j0];
        acc[0][0] += hv.x * wv.x; acc[0][1] += hv.x * wv.y;
        acc[0][2] += hv.x * wv.z; acc[0][3] += hv.x * wv.w;
        acc[1][0] += hv.y * wv.x; acc[1][1] += hv.y * wv.y;
        acc[1][2] += hv.y * wv.z; acc[1][3] += hv.y * wv.w;
    }
    __syncthreads();   // all Wm/Ht reads done before overlay writes

    float* C1t = Wm;            // 64 x 32
    float* roL = Wm + 2048;     // 64 x 48
    #pragma unroll
    for (int jj = 0; jj < 4; ++jj)
        #pragma unroll
        for (int rr = 0; rr < 2; ++rr)
            C1t[(j0 + jj) * 32 + r0 + rr] = silu_f(acc[rr][jj]);
    for (int i = t; i < MLP_H * HOR * NOUT; i += 256) roL[i] = ro_w[i];
    __syncthreads();

    // Stage 3: (32 x 64) @ (64 x 48), threads with tc < 12 active
    if (tc < HOR) {
        int o0 = tc * 4;
        float acc2[2][4];
        #pragma unroll
        for (int oo = 0; oo < 4; ++oo) { acc2[0][oo] = rbL[o0 + oo]; acc2[1][oo] = rbL[o0 + oo]; }
        for (int k = 0; k < MLP_H; ++k) {
            float2 cv = *(const float2*)&C1t[k * 32 + r0];
            float4 wv = *(const float4*)&roL[k * 48 + o0];
            acc2[0][0] += cv.x * wv.x; acc2[0][1] += cv.x * wv.y;
            acc2[0][2] += cv.x * wv.z; acc2[0][3] += cv.x * wv.w;
            acc2[1][0] += cv.y * wv.x; acc2[1][1] += cv.y * wv.y;
            acc2[1][2] += cv.y * wv.z; acc2[1][3] += cv.y * wv.w;
        }
        #pragma unroll
        for (int rr = 0; rr < 2; ++rr) {
            int r = r0 + rr;
            int n = n0 + (r >> 4), b = r & 15;
            float4 v = make_float4(acc2[rr][0], acc2[rr][1], acc2[rr][2], acc2[rr][3]);
            *(float4*)&out[((((size_t)b * HOR) + tc) * NN + n) * NOUT] = v;
        }
    }
}

// ---- launch --------------------------------------------------------------

extern "C" void kernel_launch(void* const* d_in, const int* in_sizes, int n_in,
                              void* d_out, int out_size, void* d_ws, size_t ws_size,
                              hipStream_t stream)
{
    const float* x      = (const float*)d_in[0];
    const int*   ei     = (const int*)d_in[1];
    const float* ew     = (const float*)d_in[2];
    const float* conv_w = (const float*)d_in[3];
    const float* conv_b = (const float*)d_in[4];
    const float* nemb   = (const float*)d_in[5];
    const float* emb_w  = (const float*)d_in[6];
    const float* emb_b  = (const float*)d_in[7];
    const float* mlp_w  = (const float*)d_in[8];
    const float* mlp_b  = (const float*)d_in[9];
    const float* ro_w   = (const float*)d_in[10];
    const float* ro_b   = (const float*)d_in[11];
    float* out = (float*)d_out;

    char* ws = (char*)d_ws;
    size_t off = 0;
    auto alloc = [&](size_t bytes) -> char* {
        char* p = ws + off;
        off += (bytes + 255) & ~(size_t)255;
        return p;
    };

    // zeroed region (must be first)
    float* degF = (float*)alloc(NN * 4);
    float* degB = (float*)alloc(NN * 4);
    int* cntF   = (int*)alloc(NN * 4);
    int* cntB   = (int*)alloc(NN * 4);
    int* curF   = (int*)alloc(NN * 4);
    int* curB   = (int*)alloc(NN * 4);
    size_t zeroBytes = off;

    int* rowF   = (int*)alloc((NN + 1) * 4);
    int* rowB   = (int*)alloc((NN + 1) * 4);
    int* csrSF  = (int*)alloc(NE * 4);
    float* csrWF= (float*)alloc(NE * 4);
    int* csrSB  = (int*)alloc(NE * 4);
    float* csrWB= (float*)alloc(NE * 4);
    float* xt   = (float*)alloc((size_t)NN * 64 * 4);
    float* hbuf[6];
    for (int i = 0; i < 6; ++i) hbuf[i] = (float*)alloc((size_t)NN * 64 * 4);
    float* np_  = (float*)alloc((size_t)NN * OUT_CH * 4);

    hipMemsetAsync(d_ws, 0, zeroBytes, stream);

    k_deg_cnt<<<(NE + 255) / 256, 256, 0, stream>>>(ei, ew, degF, degB, cntF, cntB);
    k_scan<<<2, 1024, 0, stream>>>(cntF, cntB, rowF, rowB);
    k_scatter<<<(NE + 255) / 256, 256, 0, stream>>>(ei, ew, degF, degB, rowF, rowB,
                                                    curF, curB, csrSF, csrWF, csrSB, csrWB);
    k_transpose<<<(NN * 64 + 255) / 256, 256, 0, stream>>>(x, xt);
    k_node_part<<<NN, 128, 0, stream>>>(nemb, emb_w, emb_b, np_);

    dim3 hopGrid((NN + 3) / 4, 2);
    // level 1: xt -> h0 (fwd), xt -> h3 (bwd)
    k_hop<<<hopGrid, 256, 0, stream>>>(xt, hbuf[0], csrSF, csrWF, rowF,
                                       xt, hbuf[3], csrSB, csrWB, rowB);
    // level 2
    k_hop<<<hopGrid, 256, 0, stream>>>(hbuf[0], hbuf[1], csrSF, csrWF, rowF,
                                       hbuf[3], hbuf[4], csrSB, csrWB, rowB);
    // level 3
    k_hop<<<hopGrid, 256, 0, stream>>>(hbuf[1], hbuf[2], csrSF, csrWF, rowF,
                                       hbuf[4], hbuf[5], csrSB, csrWB, rowB);

    k_fused<<<NN / 2, 256, 0, stream>>>(xt, hbuf[0], hbuf[1], hbuf[2],
                                        hbuf[3], hbuf[4], hbuf[5],
                                        conv_w, conv_b, np_, mlp_w, mlp_b,
                                        ro_w, ro_b, out);
}

// Round 2
// 850.757 us; speedup vs baseline: 1.3373x; 1.3373x over previous
//
#include <hip/hip_runtime.h>
#include <hip/hip_bf16.h>

#define NB 16
#define NT 12
#define NN 30000
#define NF 4
#define NE 960000
#define ORDER 7
#define GOUT 18
#define OUT_CH 126
#define MLP_H 64
#define HOR 12
#define NOUT 4
#define EMB 32

typedef unsigned short u16;
typedef __attribute__((ext_vector_type(8))) short bf16x8;
typedef __attribute__((ext_vector_type(4))) float f32x4;

__device__ __forceinline__ float silu_f(float x) {
    return x / (1.0f + __expf(-x));
}

__device__ __forceinline__ u16 f2bf(float x) {
    union { __hip_bfloat16 h; u16 u; } cv;
    cv.h = __float2bfloat16(x);
    return cv.u;
}

// ---- graph preprocessing -------------------------------------------------

__global__ __launch_bounds__(256) void k_deg_cnt(
    const int* __restrict__ ei, const float* __restrict__ ew,
    float* degF, float* degB, int* cntF, int* cntB)
{
    int e = blockIdx.x * 256 + threadIdx.x;
    if (e >= NE) return;
    int s = ei[e], d = ei[NE + e];
    float w = ew[e];
    atomicAdd(&degF[d], w);
    atomicAdd(&degB[s], w);
    atomicAdd(&cntF[d], 1);
    atomicAdd(&cntB[s], 1);
}

__global__ __launch_bounds__(1024) void k_scan(
    const int* __restrict__ cntF, const int* __restrict__ cntB,
    int* __restrict__ rowF, int* __restrict__ rowB,
    float* degF, float* degB)
{
    const int* cnt = (blockIdx.x == 0) ? cntF : cntB;
    int* row = (blockIdx.x == 0) ? rowF : rowB;
    float* deg = (blockIdx.x == 0) ? degF : degB;
    __shared__ int part[1024];
    int t = threadIdx.x;
    const int CH = (NN + 1023) / 1024;
    int lo = t * CH, hi = min(lo + CH, NN);
    int s = 0;
    for (int i = lo; i < hi; ++i) s += cnt[i];
    part[t] = s;
    // deg -> invDeg in place (scatter no longer needs raw deg)
    for (int i = lo; i < hi; ++i) deg[i] = 1.0f / fmaxf(deg[i], 1e-8f);
    __syncthreads();
    if (t == 0) {
        int run = 0;
        for (int i = 0; i < 1024; ++i) { int v = part[i]; part[i] = run; run += v; }
        row[NN] = run;
    }
    __syncthreads();
    int run = part[t];
    for (int i = lo; i < hi; ++i) { row[i] = run; run += cnt[i]; }
}

__global__ __launch_bounds__(256) void k_scatter(
    const int* __restrict__ ei, const float* __restrict__ ew,
    const int* __restrict__ rowF, const int* __restrict__ rowB,
    int* curF, int* curB,
    int2* __restrict__ csrF, int2* __restrict__ csrB)
{
    int e = blockIdx.x * 256 + threadIdx.x;
    if (e >= NE) return;
    int s = ei[e], d = ei[NE + e];
    int wb = __float_as_int(ew[e]);
    int pF = rowF[d] + atomicAdd(&curF[d], 1);
    csrF[pF] = make_int2(s, wb);
    int pB = rowB[s] + atomicAdd(&curB[s], 1);
    csrB[pB] = make_int2(d, wb);
}

// ---- xt transpose: x[b, T-1, n, f] -> xt[n, b, f] ------------------------

__global__ __launch_bounds__(256) void k_transpose(
    const float* __restrict__ x, float* __restrict__ xt)
{
    int t = blockIdx.x * 256 + threadIdx.x;   // n*64 + b*4 + f
    if (t >= NN * 64) return;
    int n = t >> 6, l = t & 63;
    int b = l >> 2, f = l & 3;
    xt[t] = x[((((size_t)b * NT) + (NT - 1)) * NN + n) * NF + f];
}

// ---- node_part[n, c] = node_emb[n] @ emb_w + emb_b -----------------------

__global__ __launch_bounds__(128) void k_node_part(
    const float* __restrict__ emb, const float* __restrict__ ewt,
    const float* __restrict__ eb, float* __restrict__ np_)
{
    int n = blockIdx.x, c = threadIdx.x;
    if (c >= OUT_CH) return;
    float a = eb[c];
    #pragma unroll
    for (int k = 0; k < EMB; ++k)
        a += emb[n * EMB + k] * ewt[k * OUT_CH + c];
    np_[n * OUT_CH + c] = a;
}

// ---- one hop level (fwd + bwd halves), gather over packed CSR ------------

__global__ __launch_bounds__(256) void k_hop(
    const float* __restrict__ inF, float* __restrict__ outF,
    const int2* __restrict__ csrF, const int* __restrict__ rowF, const float* __restrict__ invF,
    const float* __restrict__ inB, float* __restrict__ outB,
    const int2* __restrict__ csrB, const int* __restrict__ rowB, const float* __restrict__ invB)
{
    int lane = threadIdx.x & 63;
    int node = blockIdx.x * 4 + (threadIdx.x >> 6);
    if (node >= NN) return;
    const float* in; float* out; const int2* cs; const int* row; const float* inv;
    if (blockIdx.y == 0) { in = inF; out = outF; cs = csrF; row = rowF; inv = invF; }
    else                 { in = inB; out = outB; cs = csrB; row = rowB; inv = invB; }
    int beg = row[node], end = row[node + 1];
    float acc0 = 0.f, acc1 = 0.f;
    int j = beg;
    for (; j + 2 <= end; j += 2) {
        int2 e0 = cs[j], e1 = cs[j + 1];
        acc0 += __int_as_float(e0.y) * in[e0.x * 64 + lane];
        acc1 += __int_as_float(e1.y) * in[e1.x * 64 + lane];
    }
    if (j < end) {
        int2 e = cs[j];
        acc0 += __int_as_float(e.y) * in[e.x * 64 + lane];
    }
    out[node * 64 + lane] = (acc0 + acc1) * inv[node];
}

// ---- fused conv + silu + emb + mlp + silu + readout (MFMA bf16) ----------
// block: 256 threads (4 waves), 4 nodes -> 64 rows (4 nodes x 16 batches)
// row r = node_local*16 + batch

__global__ __launch_bounds__(256) void k_fused(
    const float* __restrict__ xt, const float* __restrict__ h1,
    const float* __restrict__ h2, const float* __restrict__ h3,
    const float* __restrict__ h4, const float* __restrict__ h5,
    const float* __restrict__ h6,
    const float* __restrict__ conv_w, const float* __restrict__ conv_b,
    const float* __restrict__ np_, const float* __restrict__ mlp_w,
    const float* __restrict__ mlp_b, const float* __restrict__ ro_w,
    const float* __restrict__ ro_b, float* __restrict__ out)
{
    // K-subtiled bf16 layouts for MFMA: buf[(k>>3)*R + r]*8 + (k&7)
    __shared__ __align__(16) u16 HtB[8192];    // H   (K=128 x 64 rows); aliased by C2L later
    __shared__ __align__(16) u16 WmB[8192];    // mlp_w (K=128 x 64 cols)
    __shared__ __align__(16) u16 C1B[4096];    // h2  (K=64 x 64 rows)
    __shared__ __align__(16) u16 RoB[3072];    // ro_w (K=64 x 48 cols)
    __shared__ __align__(16) float hopsL[1792];   // [7][64 rows][4 f]
    __shared__ __align__(16) float convwT[504];   // [g][q][i]
    __shared__ __align__(16) float npL[512];      // [4 nodes][128 ch] (padded)
    __shared__ float cbL[126];
    __shared__ float mbL[64];
    __shared__ float rbL[48];

    const int t = threadIdx.x;
    const int n0 = blockIdx.x * 4;
    const int lane = t & 63;
    const int w = t >> 6;
    const int lg = lane >> 4, lm = lane & 15;

    // ---- stage 0: stage everything into LDS ----
    {
        int l6 = t & 63;
        int dst = ((t >> 6) * 16 + (l6 >> 2)) * 4 + (l6 & 3);  // (nl*16+b)*4+f
        hopsL[0 * 256 + dst] = xt[n0 * 64 + t];
        hopsL[1 * 256 + dst] = h1[n0 * 64 + t];
        hopsL[2 * 256 + dst] = h2[n0 * 64 + t];
        hopsL[3 * 256 + dst] = h3[n0 * 64 + t];
        hopsL[4 * 256 + dst] = h4[n0 * 64 + t];
        hopsL[5 * 256 + dst] = h5[n0 * 64 + t];
        hopsL[6 * 256 + dst] = h6[n0 * 64 + t];
    }
    for (int i = t; i < 504; i += 256) {       // convwT[(g*18+q)*4+i] = conv_w[(g*4+i)*18+q]
        int g = i / 72, rem = i - g * 72, q = rem >> 2, ii = rem & 3;
        convwT[i] = conv_w[(g * 4 + ii) * 18 + q];
    }
    #pragma unroll
    for (int k = 0; k < 2; ++k) {
        int i = t + k * 256;
        int nl = i >> 7, c = i & 127;
        npL[i] = (c < 126) ? np_[(n0 + nl) * 126 + c] : 0.f;
    }
    if (t < 126) cbL[t] = conv_b[t];
    if (t < 64) mbL[t] = mlp_b[t];
    if (t < 48) rbL[t] = ro_b[t];
    {   // WmB: pack mlp_w (126x64 f32, zero-pad K to 128) as bf16 K-subtiles
        int j = t & 63, kb0 = t >> 6;
        #pragma unroll
        for (int kk = 0; kk < 4; ++kk) {
            int kch = kb0 + kk * 4;
            unsigned int wd0, wd1, wd2, wd3;
            {
                int c0 = kch * 8;
                float v0 = (c0 + 0 < 126) ? mlp_w[(c0 + 0) * 64 + j] : 0.f;
                float v1 = (c0 + 1 < 126) ? mlp_w[(c0 + 1) * 64 + j] : 0.f;
                float v2 = (c0 + 2 < 126) ? mlp_w[(c0 + 2) * 64 + j] : 0.f;
                float v3 = (c0 + 3 < 126) ? mlp_w[(c0 + 3) * 64 + j] : 0.f;
                float v4 = (c0 + 4 < 126) ? mlp_w[(c0 + 4) * 64 + j] : 0.f;
                float v5 = (c0 + 5 < 126) ? mlp_w[(c0 + 5) * 64 + j] : 0.f;
                float v6 = (c0 + 6 < 126) ? mlp_w[(c0 + 6) * 64 + j] : 0.f;
                float v7 = (c0 + 7 < 126) ? mlp_w[(c0 + 7) * 64 + j] : 0.f;
                wd0 = (unsigned)f2bf(v0) | ((unsigned)f2bf(v1) << 16);
                wd1 = (unsigned)f2bf(v2) | ((unsigned)f2bf(v3) << 16);
                wd2 = (unsigned)f2bf(v4) | ((unsigned)f2bf(v5) << 16);
                wd3 = (unsigned)f2bf(v6) | ((unsigned)f2bf(v7) << 16);
            }
            *(uint4*)&WmB[(kch * 64 + j) * 8] = make_uint4(wd0, wd1, wd2, wd3);
        }
    }
    #pragma unroll
    for (int kk = 0; kk < 2; ++kk) {   // RoB: ro_w (64x48) bf16 K-subtiles
        int i = t + kk * 256;
        if (i < 384) {
            int kch = i / 48, o = i - kch * 48;
            int k0 = kch * 8;
            unsigned int wd0 = (unsigned)f2bf(ro_w[(k0 + 0) * 48 + o]) | ((unsigned)f2bf(ro_w[(k0 + 1) * 48 + o]) << 16);
            unsigned int wd1 = (unsigned)f2bf(ro_w[(k0 + 2) * 48 + o]) | ((unsigned)f2bf(ro_w[(k0 + 3) * 48 + o]) << 16);
            unsigned int wd2 = (unsigned)f2bf(ro_w[(k0 + 4) * 48 + o]) | ((unsigned)f2bf(ro_w[(k0 + 5) * 48 + o]) << 16);
            unsigned int wd3 = (unsigned)f2bf(ro_w[(k0 + 6) * 48 + o]) | ((unsigned)f2bf(ro_w[(k0 + 7) * 48 + o]) << 16);
            *(uint4*)&RoB[(kch * 48 + o) * 8] = make_uint4(wd0, wd1, wd2, wd3);
        }
    }
    __syncthreads();

    // ---- stage 1: H[r][c] = silu(conv + cb) + node_part -> HtB bf16 ----
    {
        const int r = lane;
        const int nl = r >> 4;
        #pragma unroll
        for (int kc = 0; kc < 4; ++kc) {
            int c8 = (kc * 4 + w) * 8;
            float4 npA = *(const float4*)&npL[nl * 128 + c8];
            float4 npB = *(const float4*)&npL[nl * 128 + c8 + 4];
            unsigned int wd[4] = {0u, 0u, 0u, 0u};
            #pragma unroll
            for (int e = 0; e < 8; ++e) {
                int c = c8 + e;
                float val = 0.f;
                if (c < 126) {
                    int g = c / 18;
                    int q = c - g * 18;
                    const float4 hv = *(const float4*)&hopsL[(g * 64 + r) * 4];
                    const float4 cw = *(const float4*)&convwT[(g * 18 + q) * 4];
                    float a = cbL[c] + hv.x * cw.x + hv.y * cw.y + hv.z * cw.z + hv.w * cw.w;
                    float npv = (e == 0) ? npA.x : (e == 1) ? npA.y : (e == 2) ? npA.z : (e == 3) ? npA.w
                              : (e == 4) ? npB.x : (e == 5) ? npB.y : (e == 6) ? npB.z : npB.w;
                    val = silu_f(a) + npv;
                }
                unsigned int us = f2bf(val);
                if (e & 1) wd[e >> 1] |= (us << 16); else wd[e >> 1] |= us;
            }
            *(uint4*)&HtB[((c8 >> 3) * 64 + r) * 8] = make_uint4(wd[0], wd[1], wd[2], wd[3]);
        }
    }
    __syncthreads();

    // ---- stage 2: C1(64x64) = silu(H(64x128) @ Wm(128x64) + mb) -> C1B bf16
    {
        const int wr = w >> 1, wc = w & 1;
        float mb0 = mbL[wc * 32 + lm];
        float mb1 = mbL[wc * 32 + 16 + lm];
        f32x4 acc00 = {mb0, mb0, mb0, mb0};
        f32x4 acc01 = {mb1, mb1, mb1, mb1};
        f32x4 acc10 = {mb0, mb0, mb0, mb0};
        f32x4 acc11 = {mb1, mb1, mb1, mb1};
        #pragma unroll
        for (int kc = 0; kc < 4; ++kc) {
            const int kb = (kc * 4 + lg) * 64;
            bf16x8 a0 = *(const bf16x8*)&HtB[(kb + wr * 32 + lm) * 8];
            bf16x8 a1 = *(const bf16x8*)&HtB[(kb + wr * 32 + 16 + lm) * 8];
            bf16x8 b0 = *(const bf16x8*)&WmB[(kb + wc * 32 + lm) * 8];
            bf16x8 b1 = *(const bf16x8*)&WmB[(kb + wc * 32 + 16 + lm) * 8];
            acc00 = __builtin_amdgcn_mfma_f32_16x16x32_bf16(a0, b0, acc00, 0, 0, 0);
            acc01 = __builtin_amdgcn_mfma_f32_16x16x32_bf16(a0, b1, acc01, 0, 0, 0);
            acc10 = __builtin_amdgcn_mfma_f32_16x16x32_bf16(a1, b0, acc10, 0, 0, 0);
            acc11 = __builtin_amdgcn_mfma_f32_16x16x32_bf16(a1, b1, acc11, 0, 0, 0);
        }
        #pragma unroll
        for (int reg = 0; reg < 4; ++reg) {
            int row0 = wr * 32 + lg * 4 + reg;
            int col0 = wc * 32 + lm;
            C1B[((col0 >> 3) * 64 + row0) * 8 + (col0 & 7)] = f2bf(silu_f(acc00[reg]));
            int col1 = col0 + 16;
            C1B[((col1 >> 3) * 64 + row0) * 8 + (col1 & 7)] = f2bf(silu_f(acc01[reg]));
            int row1 = row0 + 16;
            C1B[((col0 >> 3) * 64 + row1) * 8 + (col0 & 7)] = f2bf(silu_f(acc10[reg]));
            C1B[((col1 >> 3) * 64 + row1) * 8 + (col1 & 7)] = f2bf(silu_f(acc11[reg]));
        }
    }
    __syncthreads();

    // ---- stage 3: C2(64x48) = C1(64x64) @ Ro(64x48) + rb ----
    {
        const int rt3 = w * 16;
        float r0 = rbL[lm], r1 = rbL[16 + lm], r2 = rbL[32 + lm];
        f32x4 c0 = {r0, r0, r0, r0};
        f32x4 c1 = {r1, r1, r1, r1};
        f32x4 c2 = {r2, r2, r2, r2};
        #pragma unroll
        for (int kc = 0; kc < 2; ++kc) {
            const int kb = kc * 4 + lg;
            bf16x8 a  = *(const bf16x8*)&C1B[(kb * 64 + rt3 + lm) * 8];
            bf16x8 b0 = *(const bf16x8*)&RoB[(kb * 48 + lm) * 8];
            bf16x8 b1 = *(const bf16x8*)&RoB[(kb * 48 + 16 + lm) * 8];
            bf16x8 b2 = *(const bf16x8*)&RoB[(kb * 48 + 32 + lm) * 8];
            c0 = __builtin_amdgcn_mfma_f32_16x16x32_bf16(a, b0, c0, 0, 0, 0);
            c1 = __builtin_amdgcn_mfma_f32_16x16x32_bf16(a, b1, c1, 0, 0, 0);
            c2 = __builtin_amdgcn_mfma_f32_16x16x32_bf16(a, b2, c2, 0, 0, 0);
        }
        float* C2L = (float*)HtB;   // HtB dead after stage 2 (barrier passed)
        #pragma unroll
        for (int reg = 0; reg < 4; ++reg) {
            int row = rt3 + lg * 4 + reg;
            C2L[row * 52 + lm]      = c0[reg];
            C2L[row * 52 + 16 + lm] = c1[reg];
            C2L[row * 52 + 32 + lm] = c2[reg];
        }
    }
    __syncthreads();

    // ---- output: out[b][hor][n][o], 64B-contiguous chunks per (b,hor) ----
    if (t < 192) {
        int b = t / 12, hor = t - b * 12;
        const float* C2L = (const float*)HtB;
        #pragma unroll
        for (int nl = 0; nl < 4; ++nl) {
            float4 v = *(const float4*)&C2L[(nl * 16 + b) * 52 + hor * 4];
            *(float4*)&out[(((size_t)b * 12 + hor) * 30000 + n0 + nl) * 4] = v;
        }
    }
}

// ---- launch --------------------------------------------------------------

extern "C" void kernel_launch(void* const* d_in, const int* in_sizes, int n_in,
                              void* d_out, int out_size, void* d_ws, size_t ws_size,
                              hipStream_t stream)
{
    const float* x      = (const float*)d_in[0];
    const int*   ei     = (const int*)d_in[1];
    const float* ew     = (const float*)d_in[2];
    const float* conv_w = (const float*)d_in[3];
    const float* conv_b = (const float*)d_in[4];
    const float* nemb   = (const float*)d_in[5];
    const float* emb_w  = (const float*)d_in[6];
    const float* emb_b  = (const float*)d_in[7];
    const float* mlp_w  = (const float*)d_in[8];
    const float* mlp_b  = (const float*)d_in[9];
    const float* ro_w   = (const float*)d_in[10];
    const float* ro_b   = (const float*)d_in[11];
    float* out = (float*)d_out;

    char* ws = (char*)d_ws;
    size_t off = 0;
    auto alloc = [&](size_t bytes) -> char* {
        char* p = ws + off;
        off += (bytes + 255) & ~(size_t)255;
        return p;
    };

    // zeroed region (must be first)
    float* degF = (float*)alloc(NN * 4);
    float* degB = (float*)alloc(NN * 4);
    int* cntF   = (int*)alloc(NN * 4);
    int* cntB   = (int*)alloc(NN * 4);
    int* curF   = (int*)alloc(NN * 4);
    int* curB   = (int*)alloc(NN * 4);
    size_t zeroBytes = off;

    int* rowF   = (int*)alloc((NN + 1) * 4);
    int* rowB   = (int*)alloc((NN + 1) * 4);
    int2* csrF  = (int2*)alloc((size_t)NE * 8);
    int2* csrB  = (int2*)alloc((size_t)NE * 8);
    float* xt   = (float*)alloc((size_t)NN * 64 * 4);
    float* hbuf[6];
    for (int i = 0; i < 6; ++i) hbuf[i] = (float*)alloc((size_t)NN * 64 * 4);
    float* np_  = (float*)alloc((size_t)NN * OUT_CH * 4);

    hipMemsetAsync(d_ws, 0, zeroBytes, stream);

    k_deg_cnt<<<(NE + 255) / 256, 256, 0, stream>>>(ei, ew, degF, degB, cntF, cntB);
    k_scan<<<2, 1024, 0, stream>>>(cntF, cntB, rowF, rowB, degF, degB);
    k_scatter<<<(NE + 255) / 256, 256, 0, stream>>>(ei, ew, rowF, rowB,
                                                    curF, curB, csrF, csrB);
    k_transpose<<<(NN * 64 + 255) / 256, 256, 0, stream>>>(x, xt);
    k_node_part<<<NN, 128, 0, stream>>>(nemb, emb_w, emb_b, np_);

    dim3 hopGrid((NN + 3) / 4, 2);
    k_hop<<<hopGrid, 256, 0, stream>>>(xt, hbuf[0], csrF, rowF, degF,
                                       xt, hbuf[3], csrB, rowB, degB);
    k_hop<<<hopGrid, 256, 0, stream>>>(hbuf[0], hbuf[1], csrF, rowF, degF,
                                       hbuf[3], hbuf[4], csrB, rowB, degB);
    k_hop<<<hopGrid, 256, 0, stream>>>(hbuf[1], hbuf[2], csrF, rowF, degF,
                                       hbuf[4], hbuf[5], csrB, rowB, degB);

    k_fused<<<NN / 4, 256, 0, stream>>>(xt, hbuf[0], hbuf[1], hbuf[2],
                                        hbuf[3], hbuf[4], hbuf[5],
                                        conv_w, conv_b, np_, mlp_w, mlp_b,
                                        ro_w, ro_b, out);
}

// Round 3
// 823.697 us; speedup vs baseline: 1.3812x; 1.0329x over previous
//
#include <hip/hip_runtime.h>
#include <hip/hip_bf16.h>

#define NB 16
#define NT 12
#define NN 30000
#define NF 4
#define NE 960000
#define ORDER 7
#define GOUT 18
#define OUT_CH 126
#define MLP_H 64
#define HOR 12
#define NOUT 4
#define EMB 32

typedef unsigned short u16;
typedef __attribute__((ext_vector_type(8))) short bf16x8;
typedef __attribute__((ext_vector_type(4))) float f32x4;

__device__ __forceinline__ float silu_f(float x) {
    return x / (1.0f + __expf(-x));
}

__device__ __forceinline__ u16 f2bf(float x) {
    union { __hip_bfloat16 h; u16 u; } cv;
    cv.h = __float2bfloat16(x);
    return cv.u;
}

__device__ __forceinline__ float bf2f(u16 us) {
    return __uint_as_float(((unsigned)us) << 16);
}

// ---- graph preprocessing -------------------------------------------------

__global__ __launch_bounds__(256) void k_deg_cnt(
    const int* __restrict__ ei, const float* __restrict__ ew,
    float* degF, float* degB, int* cntF, int* cntB)
{
    int e = blockIdx.x * 256 + threadIdx.x;
    if (e >= NE) return;
    int s = __builtin_nontemporal_load(&ei[e]);
    int d = __builtin_nontemporal_load(&ei[NE + e]);
    float w = __builtin_nontemporal_load(&ew[e]);
    atomicAdd(&degF[d], w);
    atomicAdd(&degB[s], w);
    atomicAdd(&cntF[d], 1);
    atomicAdd(&cntB[s], 1);
}

__global__ __launch_bounds__(1024) void k_scan(
    const int* __restrict__ cntF, const int* __restrict__ cntB,
    int* __restrict__ rowF, int* __restrict__ rowB,
    float* degF, float* degB)
{
    const int* cnt = (blockIdx.x == 0) ? cntF : cntB;
    int* row = (blockIdx.x == 0) ? rowF : rowB;
    float* deg = (blockIdx.x == 0) ? degF : degB;
    __shared__ int part[1024];
    int t = threadIdx.x;
    const int CH = (NN + 1023) / 1024;
    int lo = t * CH, hi = min(lo + CH, NN);
    int s = 0;
    for (int i = lo; i < hi; ++i) s += cnt[i];
    part[t] = s;
    for (int i = lo; i < hi; ++i) deg[i] = 1.0f / fmaxf(deg[i], 1e-8f);
    __syncthreads();
    if (t == 0) {
        int run = 0;
        for (int i = 0; i < 1024; ++i) { int v = part[i]; part[i] = run; run += v; }
        row[NN] = run;
    }
    __syncthreads();
    int run = part[t];
    for (int i = lo; i < hi; ++i) { row[i] = run; run += cnt[i]; }
}

__global__ __launch_bounds__(256) void k_scatter(
    const int* __restrict__ ei, const float* __restrict__ ew,
    const int* __restrict__ rowF, const int* __restrict__ rowB,
    int* curF, int* curB,
    int2* __restrict__ csrF, int2* __restrict__ csrB)
{
    int e = blockIdx.x * 256 + threadIdx.x;
    if (e >= NE) return;
    int s = __builtin_nontemporal_load(&ei[e]);
    int d = __builtin_nontemporal_load(&ei[NE + e]);
    int wb = __float_as_int(__builtin_nontemporal_load(&ew[e]));
    int pF = rowF[d] + atomicAdd(&curF[d], 1);
    csrF[pF] = make_int2(s, wb);
    int pB = rowB[s] + atomicAdd(&curB[s], 1);
    csrB[pB] = make_int2(d, wb);
}

// ---- xt transpose: x[b, T-1, n, f] -> xtF[n,b,f] f32 + xtB bf16 ----------

__global__ __launch_bounds__(256) void k_transpose(
    const float* __restrict__ x, float* __restrict__ xtF, u16* __restrict__ xtB)
{
    int t = blockIdx.x * 256 + threadIdx.x;   // n*64 + b*4 + f
    if (t >= NN * 64) return;
    int n = t >> 6, l = t & 63;
    int b = l >> 2, f = l & 3;
    float v = __builtin_nontemporal_load(&x[((((size_t)b * NT) + (NT - 1)) * NN + n) * NF + f]);
    xtF[t] = v;
    xtB[t] = f2bf(v);
}

// ---- one-time weight packing ----------------------------------------------
// block 0: WmG  (mlp_w 126x64 -> bf16, K padded to 128, K-subtiled)
// block 1: RoG  (ro_w 64x48 -> bf16, K-subtiled)
// block 2: cwT  (conv_w transposed [g][q][i])
// block 3: ewT  (emb_w transposed [c][k])

__global__ __launch_bounds__(256) void k_pack(
    const float* __restrict__ mlp_w, const float* __restrict__ ro_w,
    const float* __restrict__ conv_w, const float* __restrict__ emb_w,
    u16* __restrict__ WmG, u16* __restrict__ RoG,
    float* __restrict__ cwT, float* __restrict__ ewT)
{
    int t = threadIdx.x;
    if (blockIdx.x == 0) {
        int j = t & 63, kb0 = t >> 6;
        #pragma unroll
        for (int kk = 0; kk < 4; ++kk) {
            int kch = kb0 + kk * 4;
            int c0 = kch * 8;
            float v[8];
            #pragma unroll
            for (int e = 0; e < 8; ++e)
                v[e] = (c0 + e < 126) ? mlp_w[(c0 + e) * 64 + j] : 0.f;
            unsigned int wd0 = (unsigned)f2bf(v[0]) | ((unsigned)f2bf(v[1]) << 16);
            unsigned int wd1 = (unsigned)f2bf(v[2]) | ((unsigned)f2bf(v[3]) << 16);
            unsigned int wd2 = (unsigned)f2bf(v[4]) | ((unsigned)f2bf(v[5]) << 16);
            unsigned int wd3 = (unsigned)f2bf(v[6]) | ((unsigned)f2bf(v[7]) << 16);
            *(uint4*)&WmG[(kch * 64 + j) * 8] = make_uint4(wd0, wd1, wd2, wd3);
        }
    } else if (blockIdx.x == 1) {
        #pragma unroll
        for (int kk = 0; kk < 2; ++kk) {
            int i = t + kk * 256;
            if (i < 384) {
                int kch = i / 48, o = i - kch * 48;
                int k0 = kch * 8;
                unsigned int wd0 = (unsigned)f2bf(ro_w[(k0 + 0) * 48 + o]) | ((unsigned)f2bf(ro_w[(k0 + 1) * 48 + o]) << 16);
                unsigned int wd1 = (unsigned)f2bf(ro_w[(k0 + 2) * 48 + o]) | ((unsigned)f2bf(ro_w[(k0 + 3) * 48 + o]) << 16);
                unsigned int wd2 = (unsigned)f2bf(ro_w[(k0 + 4) * 48 + o]) | ((unsigned)f2bf(ro_w[(k0 + 5) * 48 + o]) << 16);
                unsigned int wd3 = (unsigned)f2bf(ro_w[(k0 + 6) * 48 + o]) | ((unsigned)f2bf(ro_w[(k0 + 7) * 48 + o]) << 16);
                *(uint4*)&RoG[(kch * 48 + o) * 8] = make_uint4(wd0, wd1, wd2, wd3);
            }
        }
    } else if (blockIdx.x == 2) {
        for (int i = t; i < 504; i += 256) {
            int g = i / 72, rem = i - g * 72, q = rem >> 2, ii = rem & 3;
            cwT[i] = conv_w[(g * 4 + ii) * 18 + q];
        }
    } else {
        for (int i = t; i < 4032; i += 256) {
            int c = i >> 5, k = i & 31;
            ewT[i] = emb_w[k * 126 + c];
        }
    }
}

// ---- one hop level (fwd + bwd halves), bf16 gather over packed CSR -------

__global__ __launch_bounds__(256) void k_hop(
    const u16* __restrict__ inF, u16* __restrict__ outF,
    const int2* __restrict__ csrF, const int* __restrict__ rowF, const float* __restrict__ invF,
    const u16* __restrict__ inB, u16* __restrict__ outB,
    const int2* __restrict__ csrB, const int* __restrict__ rowB, const float* __restrict__ invB)
{
    int lane = threadIdx.x & 63;
    int node = blockIdx.x * 4 + (threadIdx.x >> 6);
    if (node >= NN) return;
    const u16* in; u16* out; const int2* cs; const int* row; const float* inv;
    if (blockIdx.y == 0) { in = inF; out = outF; cs = csrF; row = rowF; inv = invF; }
    else                 { in = inB; out = outB; cs = csrB; row = rowB; inv = invB; }
    int beg = row[node], end = row[node + 1];
    float a0 = 0.f, a1 = 0.f, a2 = 0.f, a3 = 0.f;
    int j = beg;
    for (; j + 4 <= end; j += 4) {
        long long v0 = __builtin_nontemporal_load((const long long*)&cs[j]);
        long long v1 = __builtin_nontemporal_load((const long long*)&cs[j + 1]);
        long long v2 = __builtin_nontemporal_load((const long long*)&cs[j + 2]);
        long long v3 = __builtin_nontemporal_load((const long long*)&cs[j + 3]);
        int s0 = (int)v0; float w0 = __int_as_float((int)(v0 >> 32));
        int s1 = (int)v1; float w1 = __int_as_float((int)(v1 >> 32));
        int s2 = (int)v2; float w2 = __int_as_float((int)(v2 >> 32));
        int s3 = (int)v3; float w3 = __int_as_float((int)(v3 >> 32));
        a0 += w0 * bf2f(in[s0 * 64 + lane]);
        a1 += w1 * bf2f(in[s1 * 64 + lane]);
        a2 += w2 * bf2f(in[s2 * 64 + lane]);
        a3 += w3 * bf2f(in[s3 * 64 + lane]);
    }
    for (; j < end; ++j) {
        long long v = __builtin_nontemporal_load((const long long*)&cs[j]);
        int s = (int)v; float w = __int_as_float((int)(v >> 32));
        a0 += w * bf2f(in[s * 64 + lane]);
    }
    out[node * 64 + lane] = f2bf(((a0 + a1) + (a2 + a3)) * inv[node]);
}

// ---- fused conv + silu + emb + mlp + silu + readout (MFMA bf16) ----------
// block: 256 threads (4 waves), 4 nodes -> 64 rows (4 nodes x 16 batches)

__global__ __launch_bounds__(256) void k_fused(
    const float* __restrict__ xtF,
    const u16* __restrict__ h1, const u16* __restrict__ h2,
    const u16* __restrict__ h3, const u16* __restrict__ h4,
    const u16* __restrict__ h5, const u16* __restrict__ h6,
    const u16* __restrict__ WmG, const u16* __restrict__ RoG,
    const float* __restrict__ cwT, const float* __restrict__ ewT,
    const float* __restrict__ nemb,
    const float* __restrict__ conv_b, const float* __restrict__ emb_b,
    const float* __restrict__ mlp_b, const float* __restrict__ ro_b,
    float* __restrict__ out)
{
    __shared__ __align__(16) u16 HtB[8192];      // 16KB; aliased as C2L (f32) later
    __shared__ __align__(16) u16 C1B[4096];      // 8KB
    __shared__ __align__(16) float hopsL[1792];  // [7][64 rows][4 f]
    __shared__ __align__(16) float convwL[504];  // [g][q][i]
    __shared__ __align__(16) float npL[512];     // [4 nodes][128 ch]
    __shared__ float cbL[128];
    __shared__ float mbL[64];
    __shared__ float rbL[48];

    const int t = threadIdx.x;
    const int n0 = blockIdx.x * 4;
    const int lane = t & 63;
    const int w = t >> 6;
    const int lg = lane >> 4, lm = lane & 15;

    // ---- stage 0: stage activations + compute node_part ----
    {
        int l6 = t & 63;
        int dst = ((t >> 6) * 16 + (l6 >> 2)) * 4 + (l6 & 3);  // (nl*16+b)*4+f
        hopsL[0 * 256 + dst] = xtF[n0 * 64 + t];
        hopsL[1 * 256 + dst] = bf2f(h1[n0 * 64 + t]);
        hopsL[2 * 256 + dst] = bf2f(h2[n0 * 64 + t]);
        hopsL[3 * 256 + dst] = bf2f(h3[n0 * 64 + t]);
        hopsL[4 * 256 + dst] = bf2f(h4[n0 * 64 + t]);
        hopsL[5 * 256 + dst] = bf2f(h5[n0 * 64 + t]);
        hopsL[6 * 256 + dst] = bf2f(h6[n0 * 64 + t]);
    }
    for (int i = t; i < 504; i += 256) convwL[i] = cwT[i];
    if (t < 126) cbL[t] = conv_b[t];
    if (t < 64) mbL[t] = mlp_b[t];
    if (t < 48) rbL[t] = ro_b[t];
    #pragma unroll
    for (int kk = 0; kk < 2; ++kk) {   // npL[nl*128+c] = emb_b[c] + emb[n0+nl] . ewT[c]
        int i = t + kk * 256;
        int nl = i >> 7, c = i & 127;
        float a = 0.f;
        if (c < 126) {
            a = emb_b[c];
            const float4* em = (const float4*)&nemb[(size_t)(n0 + nl) * 32];
            const float4* ec = (const float4*)&ewT[c * 32];
            #pragma unroll
            for (int q = 0; q < 8; ++q) {
                float4 e4 = em[q], w4 = ec[q];
                a += e4.x * w4.x + e4.y * w4.y + e4.z * w4.z + e4.w * w4.w;
            }
        }
        npL[i] = a;
    }
    __syncthreads();

    // ---- stage 1: H[r][c] = silu(conv + cb) + node_part -> HtB bf16 ----
    {
        const int r = lane;
        const int nl = r >> 4;
        #pragma unroll
        for (int kc = 0; kc < 4; ++kc) {
            int c8 = (kc * 4 + w) * 8;
            float4 npA = *(const float4*)&npL[nl * 128 + c8];
            float4 npB = *(const float4*)&npL[nl * 128 + c8 + 4];
            unsigned int wd[4] = {0u, 0u, 0u, 0u};
            #pragma unroll
            for (int e = 0; e < 8; ++e) {
                int c = c8 + e;
                float val = 0.f;
                if (c < 126) {
                    int g = c / 18;
                    int q = c - g * 18;
                    const float4 hv = *(const float4*)&hopsL[(g * 64 + r) * 4];
                    const float4 cw = *(const float4*)&convwL[(g * 18 + q) * 4];
                    float a = cbL[c] + hv.x * cw.x + hv.y * cw.y + hv.z * cw.z + hv.w * cw.w;
                    float npv = (e == 0) ? npA.x : (e == 1) ? npA.y : (e == 2) ? npA.z : (e == 3) ? npA.w
                              : (e == 4) ? npB.x : (e == 5) ? npB.y : (e == 6) ? npB.z : npB.w;
                    val = silu_f(a) + npv;
                }
                unsigned int us = f2bf(val);
                if (e & 1) wd[e >> 1] |= (us << 16); else wd[e >> 1] |= us;
            }
            *(uint4*)&HtB[((c8 >> 3) * 64 + r) * 8] = make_uint4(wd[0], wd[1], wd[2], wd[3]);
        }
    }
    __syncthreads();

    // ---- stage 2: C1(64x64) = silu(H(64x128) @ Wm(128x64) + mb) -> C1B bf16
    {
        const int wr = w >> 1, wc = w & 1;
        float mb0 = mbL[wc * 32 + lm];
        float mb1 = mbL[wc * 32 + 16 + lm];
        f32x4 acc00 = {mb0, mb0, mb0, mb0};
        f32x4 acc01 = {mb1, mb1, mb1, mb1};
        f32x4 acc10 = {mb0, mb0, mb0, mb0};
        f32x4 acc11 = {mb1, mb1, mb1, mb1};
        #pragma unroll
        for (int kc = 0; kc < 4; ++kc) {
            const int kb = (kc * 4 + lg) * 64;
            bf16x8 a0 = *(const bf16x8*)&HtB[(kb + wr * 32 + lm) * 8];
            bf16x8 a1 = *(const bf16x8*)&HtB[(kb + wr * 32 + 16 + lm) * 8];
            bf16x8 b0 = *(const bf16x8*)&WmG[(kb + wc * 32 + lm) * 8];
            bf16x8 b1 = *(const bf16x8*)&WmG[(kb + wc * 32 + 16 + lm) * 8];
            acc00 = __builtin_amdgcn_mfma_f32_16x16x32_bf16(a0, b0, acc00, 0, 0, 0);
            acc01 = __builtin_amdgcn_mfma_f32_16x16x32_bf16(a0, b1, acc01, 0, 0, 0);
            acc10 = __builtin_amdgcn_mfma_f32_16x16x32_bf16(a1, b0, acc10, 0, 0, 0);
            acc11 = __builtin_amdgcn_mfma_f32_16x16x32_bf16(a1, b1, acc11, 0, 0, 0);
        }
        #pragma unroll
        for (int reg = 0; reg < 4; ++reg) {
            int row0 = wr * 32 + lg * 4 + reg;
            int col0 = wc * 32 + lm;
            C1B[((col0 >> 3) * 64 + row0) * 8 + (col0 & 7)] = f2bf(silu_f(acc00[reg]));
            int col1 = col0 + 16;
            C1B[((col1 >> 3) * 64 + row0) * 8 + (col1 & 7)] = f2bf(silu_f(acc01[reg]));
            int row1 = row0 + 16;
            C1B[((col0 >> 3) * 64 + row1) * 8 + (col0 & 7)] = f2bf(silu_f(acc10[reg]));
            C1B[((col1 >> 3) * 64 + row1) * 8 + (col1 & 7)] = f2bf(silu_f(acc11[reg]));
        }
    }
    __syncthreads();

    // ---- stage 3: C2(64x48) = C1(64x64) @ Ro(64x48) + rb ----
    {
        const int rt3 = w * 16;
        float r0 = rbL[lm], r1 = rbL[16 + lm], r2 = rbL[32 + lm];
        f32x4 c0 = {r0, r0, r0, r0};
        f32x4 c1 = {r1, r1, r1, r1};
        f32x4 c2 = {r2, r2, r2, r2};
        #pragma unroll
        for (int kc = 0; kc < 2; ++kc) {
            const int kb = kc * 4 + lg;
            bf16x8 a  = *(const bf16x8*)&C1B[(kb * 64 + rt3 + lm) * 8];
            bf16x8 b0 = *(const bf16x8*)&RoG[(kb * 48 + lm) * 8];
            bf16x8 b1 = *(const bf16x8*)&RoG[(kb * 48 + 16 + lm) * 8];
            bf16x8 b2 = *(const bf16x8*)&RoG[(kb * 48 + 32 + lm) * 8];
            c0 = __builtin_amdgcn_mfma_f32_16x16x32_bf16(a, b0, c0, 0, 0, 0);
            c1 = __builtin_amdgcn_mfma_f32_16x16x32_bf16(a, b1, c1, 0, 0, 0);
            c2 = __builtin_amdgcn_mfma_f32_16x16x32_bf16(a, b2, c2, 0, 0, 0);
        }
        float* C2L = (float*)HtB;   // HtB dead after stage 2
        #pragma unroll
        for (int reg = 0; reg < 4; ++reg) {
            int row = rt3 + lg * 4 + reg;
            C2L[row * 52 + lm]      = c0[reg];
            C2L[row * 52 + 16 + lm] = c1[reg];
            C2L[row * 52 + 32 + lm] = c2[reg];
        }
    }
    __syncthreads();

    // ---- output: out[b][hor][n][o] ----
    if (t < 192) {
        int b = t / 12, hor = t - b * 12;
        const float* C2L = (const float*)HtB;
        #pragma unroll
        for (int nl = 0; nl < 4; ++nl) {
            f32x4 v = *(const f32x4*)&C2L[(nl * 16 + b) * 52 + hor * 4];
            __builtin_nontemporal_store(v, (f32x4*)&out[(((size_t)b * 12 + hor) * 30000 + n0 + nl) * 4]);
        }
    }
}

// ---- launch --------------------------------------------------------------

extern "C" void kernel_launch(void* const* d_in, const int* in_sizes, int n_in,
                              void* d_out, int out_size, void* d_ws, size_t ws_size,
                              hipStream_t stream)
{
    const float* x      = (const float*)d_in[0];
    const int*   ei     = (const int*)d_in[1];
    const float* ew     = (const float*)d_in[2];
    const float* conv_w = (const float*)d_in[3];
    const float* conv_b = (const float*)d_in[4];
    const float* nemb   = (const float*)d_in[5];
    const float* emb_w  = (const float*)d_in[6];
    const float* emb_b  = (const float*)d_in[7];
    const float* mlp_w  = (const float*)d_in[8];
    const float* mlp_b  = (const float*)d_in[9];
    const float* ro_w   = (const float*)d_in[10];
    const float* ro_b   = (const float*)d_in[11];
    float* out = (float*)d_out;

    char* ws = (char*)d_ws;
    size_t off = 0;
    auto alloc = [&](size_t bytes) -> char* {
        char* p = ws + off;
        off += (bytes + 255) & ~(size_t)255;
        return p;
    };

    // zeroed region (must be first)
    float* degF = (float*)alloc(NN * 4);
    float* degB = (float*)alloc(NN * 4);
    int* cntF   = (int*)alloc(NN * 4);
    int* cntB   = (int*)alloc(NN * 4);
    int* curF   = (int*)alloc(NN * 4);
    int* curB   = (int*)alloc(NN * 4);
    size_t zeroBytes = off;

    int* rowF   = (int*)alloc((NN + 1) * 4);
    int* rowB   = (int*)alloc((NN + 1) * 4);
    int2* csrF  = (int2*)alloc((size_t)NE * 8);
    int2* csrB  = (int2*)alloc((size_t)NE * 8);
    float* xtF  = (float*)alloc((size_t)NN * 64 * 4);
    u16* xtB    = (u16*)alloc((size_t)NN * 64 * 2);
    u16* hbuf[6];
    for (int i = 0; i < 6; ++i) hbuf[i] = (u16*)alloc((size_t)NN * 64 * 2);
    u16* WmG    = (u16*)alloc(8192 * 2);
    u16* RoG    = (u16*)alloc(3072 * 2);
    float* cwT  = (float*)alloc(504 * 4);
    float* ewT  = (float*)alloc(4032 * 4);

    hipMemsetAsync(d_ws, 0, zeroBytes, stream);

    k_pack<<<4, 256, 0, stream>>>(mlp_w, ro_w, conv_w, emb_w, WmG, RoG, cwT, ewT);
    k_deg_cnt<<<(NE + 255) / 256, 256, 0, stream>>>(ei, ew, degF, degB, cntF, cntB);
    k_scan<<<2, 1024, 0, stream>>>(cntF, cntB, rowF, rowB, degF, degB);
    k_scatter<<<(NE + 255) / 256, 256, 0, stream>>>(ei, ew, rowF, rowB,
                                                    curF, curB, csrF, csrB);
    k_transpose<<<(NN * 64 + 255) / 256, 256, 0, stream>>>(x, xtF, xtB);

    dim3 hopGrid((NN + 3) / 4, 2);
    k_hop<<<hopGrid, 256, 0, stream>>>(xtB, hbuf[0], csrF, rowF, degF,
                                       xtB, hbuf[3], csrB, rowB, degB);
    k_hop<<<hopGrid, 256, 0, stream>>>(hbuf[0], hbuf[1], csrF, rowF, degF,
                                       hbuf[3], hbuf[4], csrB, rowB, degB);
    k_hop<<<hopGrid, 256, 0, stream>>>(hbuf[1], hbuf[2], csrF, rowF, degF,
                                       hbuf[4], hbuf[5], csrB, rowB, degB);

    k_fused<<<NN / 4, 256, 0, stream>>>(xtF, hbuf[0], hbuf[1], hbuf[2],
                                        hbuf[3], hbuf[4], hbuf[5],
                                        WmG, RoG, cwT, ewT, nemb,
                                        conv_b, emb_b, mlp_b, ro_b, out);
}

// Round 4
// 605.462 us; speedup vs baseline: 1.8790x; 1.3604x over previous
//
#include <hip/hip_runtime.h>
#include <hip/hip_bf16.h>

#define NB 16
#define NT 12
#define NN 30000
#define NF 4
#define NE 960000
#define ORDER 7
#define GOUT 18
#define OUT_CH 126
#define MLP_H 64
#define HOR 12
#define NOUT 4
#define EMB 32

typedef unsigned short u16;
typedef __attribute__((ext_vector_type(8))) short bf16x8;
typedef __attribute__((ext_vector_type(4))) float f32x4;

__device__ __forceinline__ float silu_f(float x) {
    return x / (1.0f + __expf(-x));
}

__device__ __forceinline__ u16 f2bf(float x) {
    union { __hip_bfloat16 h; u16 u; } cv;
    cv.h = __float2bfloat16(x);
    return cv.u;
}

__device__ __forceinline__ float bf2f(u16 us) {
    return __uint_as_float(((unsigned)us) << 16);
}

// ---- graph preprocessing -------------------------------------------------

__global__ __launch_bounds__(256) void k_cnt(
    const int* __restrict__ ei, int* cntF, int* cntB)
{
    int e = blockIdx.x * 256 + threadIdx.x;
    if (e >= NE) return;
    int s = __builtin_nontemporal_load(&ei[e]);
    int d = __builtin_nontemporal_load(&ei[NE + e]);
    atomicAdd(&cntF[d], 1);
    atomicAdd(&cntB[s], 1);
}

__global__ __launch_bounds__(1024) void k_scan(
    const int* __restrict__ cntF, const int* __restrict__ cntB,
    int* __restrict__ rowF, int* __restrict__ rowB)
{
    const int* cnt = (blockIdx.x == 0) ? cntF : cntB;
    int* row = (blockIdx.x == 0) ? rowF : rowB;
    __shared__ int part[1024];
    int t = threadIdx.x;
    const int CH = (NN + 1023) / 1024;
    int lo = t * CH, hi = min(lo + CH, NN);
    int s = 0;
    for (int i = lo; i < hi; ++i) s += cnt[i];
    part[t] = s;
    __syncthreads();
    if (t == 0) {
        int run = 0;
        for (int i = 0; i < 1024; ++i) { int v = part[i]; part[i] = run; run += v; }
        row[NN] = run;
    }
    __syncthreads();
    int run = part[t];
    for (int i = lo; i < hi; ++i) { row[i] = run; run += cnt[i]; }
}

__global__ __launch_bounds__(256) void k_scatter(
    const int* __restrict__ ei, const float* __restrict__ ew,
    const int* __restrict__ rowF, const int* __restrict__ rowB,
    int* curF, int* curB,
    int2* __restrict__ csrF, int2* __restrict__ csrB)
{
    int e = blockIdx.x * 256 + threadIdx.x;
    if (e >= NE) return;
    int s = __builtin_nontemporal_load(&ei[e]);
    int d = __builtin_nontemporal_load(&ei[NE + e]);
    int wb = __float_as_int(__builtin_nontemporal_load(&ew[e]));
    int pF = rowF[d] + atomicAdd(&curF[d], 1);
    csrF[pF] = make_int2(s, wb);
    int pB = rowB[s] + atomicAdd(&curB[s], 1);
    csrB[pB] = make_int2(d, wb);
}

// ---- xt transpose: x[b, T-1, n, f] -> xtF[n,b,f] f32 + xtB bf16 ----------
// one node per thread, one batch per blockIdx.y: fully coalesced float4 reads

__global__ __launch_bounds__(256) void k_transpose(
    const float* __restrict__ x, float* __restrict__ xtF, u16* __restrict__ xtB)
{
    int n = blockIdx.x * 256 + threadIdx.x;
    if (n >= NN) return;
    int b = blockIdx.y;
    float4 v = *(const float4*)&x[((((size_t)b * NT) + (NT - 1)) * NN + n) * NF];
    *(float4*)&xtF[n * 64 + b * 4] = v;
    uint2 p;
    p.x = (unsigned)f2bf(v.x) | ((unsigned)f2bf(v.y) << 16);
    p.y = (unsigned)f2bf(v.z) | ((unsigned)f2bf(v.w) << 16);
    *(uint2*)&xtB[n * 64 + b * 4] = p;
}

// ---- one-time weight packing ---------------------------------------------

__global__ __launch_bounds__(256) void k_pack(
    const float* __restrict__ mlp_w, const float* __restrict__ ro_w,
    const float* __restrict__ conv_w, const float* __restrict__ emb_w,
    u16* __restrict__ WmG, u16* __restrict__ RoG,
    float* __restrict__ cwT, float* __restrict__ ewT)
{
    int t = threadIdx.x;
    if (blockIdx.x == 0) {
        int j = t & 63, kb0 = t >> 6;
        #pragma unroll
        for (int kk = 0; kk < 4; ++kk) {
            int kch = kb0 + kk * 4;
            int c0 = kch * 8;
            float v[8];
            #pragma unroll
            for (int e = 0; e < 8; ++e)
                v[e] = (c0 + e < 126) ? mlp_w[(c0 + e) * 64 + j] : 0.f;
            unsigned int wd0 = (unsigned)f2bf(v[0]) | ((unsigned)f2bf(v[1]) << 16);
            unsigned int wd1 = (unsigned)f2bf(v[2]) | ((unsigned)f2bf(v[3]) << 16);
            unsigned int wd2 = (unsigned)f2bf(v[4]) | ((unsigned)f2bf(v[5]) << 16);
            unsigned int wd3 = (unsigned)f2bf(v[6]) | ((unsigned)f2bf(v[7]) << 16);
            *(uint4*)&WmG[(kch * 64 + j) * 8] = make_uint4(wd0, wd1, wd2, wd3);
        }
    } else if (blockIdx.x == 1) {
        #pragma unroll
        for (int kk = 0; kk < 2; ++kk) {
            int i = t + kk * 256;
            if (i < 384) {
                int kch = i / 48, o = i - kch * 48;
                int k0 = kch * 8;
                unsigned int wd0 = (unsigned)f2bf(ro_w[(k0 + 0) * 48 + o]) | ((unsigned)f2bf(ro_w[(k0 + 1) * 48 + o]) << 16);
                unsigned int wd1 = (unsigned)f2bf(ro_w[(k0 + 2) * 48 + o]) | ((unsigned)f2bf(ro_w[(k0 + 3) * 48 + o]) << 16);
                unsigned int wd2 = (unsigned)f2bf(ro_w[(k0 + 4) * 48 + o]) | ((unsigned)f2bf(ro_w[(k0 + 5) * 48 + o]) << 16);
                unsigned int wd3 = (unsigned)f2bf(ro_w[(k0 + 6) * 48 + o]) | ((unsigned)f2bf(ro_w[(k0 + 7) * 48 + o]) << 16);
                *(uint4*)&RoG[(kch * 48 + o) * 8] = make_uint4(wd0, wd1, wd2, wd3);
            }
        }
    } else if (blockIdx.x == 2) {
        for (int i = t; i < 504; i += 256) {
            int g = i / 72, rem = i - g * 72, q = rem >> 2, ii = rem & 3;
            cwT[i] = conv_w[(g * 4 + ii) * 18 + q];
        }
    } else {
        for (int i = t; i < 4032; i += 256) {
            int c = i >> 5, k = i & 31;
            ewT[i] = emb_w[k * 126 + c];
        }
    }
}

// ---- one hop level (fwd + bwd halves), bf16 gather, inline row-sum norm --

__global__ __launch_bounds__(256) void k_hop(
    const u16* __restrict__ inF, u16* __restrict__ outF,
    const int2* __restrict__ csrF, const int* __restrict__ rowF,
    const u16* __restrict__ inB, u16* __restrict__ outB,
    const int2* __restrict__ csrB, const int* __restrict__ rowB)
{
    int lane = threadIdx.x & 63;
    int node = blockIdx.x * 4 + (threadIdx.x >> 6);
    if (node >= NN) return;
    const u16* in; u16* out; const int2* cs; const int* row;
    if (blockIdx.y == 0) { in = inF; out = outF; cs = csrF; row = rowF; }
    else                 { in = inB; out = outB; cs = csrB; row = rowB; }
    int beg = row[node], end = row[node + 1];
    float a0 = 0.f, a1 = 0.f, a2 = 0.f, a3 = 0.f;
    float ws0 = 0.f, ws1 = 0.f;
    int j = beg;
    for (; j + 4 <= end; j += 4) {
        long long v0 = __builtin_nontemporal_load((const long long*)&cs[j]);
        long long v1 = __builtin_nontemporal_load((const long long*)&cs[j + 1]);
        long long v2 = __builtin_nontemporal_load((const long long*)&cs[j + 2]);
        long long v3 = __builtin_nontemporal_load((const long long*)&cs[j + 3]);
        int s0 = (int)v0; float w0 = __int_as_float((int)(v0 >> 32));
        int s1 = (int)v1; float w1 = __int_as_float((int)(v1 >> 32));
        int s2 = (int)v2; float w2 = __int_as_float((int)(v2 >> 32));
        int s3 = (int)v3; float w3 = __int_as_float((int)(v3 >> 32));
        a0 += w0 * bf2f(in[s0 * 64 + lane]);
        a1 += w1 * bf2f(in[s1 * 64 + lane]);
        a2 += w2 * bf2f(in[s2 * 64 + lane]);
        a3 += w3 * bf2f(in[s3 * 64 + lane]);
        ws0 += w0 + w1;
        ws1 += w2 + w3;
    }
    for (; j < end; ++j) {
        long long v = __builtin_nontemporal_load((const long long*)&cs[j]);
        int s = (int)v; float w = __int_as_float((int)(v >> 32));
        a0 += w * bf2f(in[s * 64 + lane]);
        ws0 += w;
    }
    float inv = 1.0f / fmaxf(ws0 + ws1, 1e-8f);
    out[node * 64 + lane] = f2bf(((a0 + a1) + (a2 + a3)) * inv);
}

// ---- fused conv + silu + emb + mlp + silu + readout (MFMA bf16) ----------
// block: 256 threads (4 waves), 4 nodes -> 64 rows (4 nodes x 16 batches)

__global__ __launch_bounds__(256) void k_fused(
    const float* __restrict__ xtF,
    const u16* __restrict__ h1, const u16* __restrict__ h2,
    const u16* __restrict__ h3, const u16* __restrict__ h4,
    const u16* __restrict__ h5, const u16* __restrict__ h6,
    const u16* __restrict__ WmG, const u16* __restrict__ RoG,
    const float* __restrict__ cwT, const float* __restrict__ ewT,
    const float* __restrict__ nemb,
    const float* __restrict__ conv_b, const float* __restrict__ emb_b,
    const float* __restrict__ mlp_b, const float* __restrict__ ro_b,
    float* __restrict__ out)
{
    __shared__ __align__(16) u16 HtB[8192];      // 16KB; aliased as C2L (f32) later
    __shared__ __align__(16) u16 C1B[4096];      // 8KB
    __shared__ __align__(16) float hopsL[1792];  // [7][64 rows][4 f]
    __shared__ __align__(16) float convwL[504];  // [g][q][i]
    __shared__ __align__(16) float npL[512];     // [4 nodes][128 ch]
    __shared__ float cbL[128];
    __shared__ float mbL[64];
    __shared__ float rbL[48];

    const int t = threadIdx.x;
    const int n0 = blockIdx.x * 4;
    const int lane = t & 63;
    const int w = t >> 6;
    const int lg = lane >> 4, lm = lane & 15;

    // ---- stage 0: stage activations + compute node_part ----
    {
        int l6 = t & 63;
        int dst = ((t >> 6) * 16 + (l6 >> 2)) * 4 + (l6 & 3);  // (nl*16+b)*4+f
        hopsL[0 * 256 + dst] = xtF[n0 * 64 + t];
        hopsL[1 * 256 + dst] = bf2f(h1[n0 * 64 + t]);
        hopsL[2 * 256 + dst] = bf2f(h2[n0 * 64 + t]);
        hopsL[3 * 256 + dst] = bf2f(h3[n0 * 64 + t]);
        hopsL[4 * 256 + dst] = bf2f(h4[n0 * 64 + t]);
        hopsL[5 * 256 + dst] = bf2f(h5[n0 * 64 + t]);
        hopsL[6 * 256 + dst] = bf2f(h6[n0 * 64 + t]);
    }
    for (int i = t; i < 504; i += 256) convwL[i] = cwT[i];
    if (t < 126) cbL[t] = conv_b[t];
    if (t < 64) mbL[t] = mlp_b[t];
    if (t < 48) rbL[t] = ro_b[t];
    #pragma unroll
    for (int kk = 0; kk < 2; ++kk) {   // npL[nl*128+c] = emb_b[c] + emb[n0+nl] . ewT[c]
        int i = t + kk * 256;
        int nl = i >> 7, c = i & 127;
        float a = 0.f;
        if (c < 126) {
            a = emb_b[c];
            const float4* em = (const float4*)&nemb[(size_t)(n0 + nl) * 32];
            const float4* ec = (const float4*)&ewT[c * 32];
            #pragma unroll
            for (int q = 0; q < 8; ++q) {
                float4 e4 = em[q], w4 = ec[q];
                a += e4.x * w4.x + e4.y * w4.y + e4.z * w4.z + e4.w * w4.w;
            }
        }
        npL[i] = a;
    }
    __syncthreads();

    // ---- stage 1: H[r][c] = silu(conv + cb) + node_part -> HtB bf16 ----
    {
        const int r = lane;
        const int nl = r >> 4;
        #pragma unroll
        for (int kc = 0; kc < 4; ++kc) {
            int c8 = (kc * 4 + w) * 8;
            float4 npA = *(const float4*)&npL[nl * 128 + c8];
            float4 npB = *(const float4*)&npL[nl * 128 + c8 + 4];
            unsigned int wd[4] = {0u, 0u, 0u, 0u};
            #pragma unroll
            for (int e = 0; e < 8; ++e) {
                int c = c8 + e;
                float val = 0.f;
                if (c < 126) {
                    int g = c / 18;
                    int q = c - g * 18;
                    const float4 hv = *(const float4*)&hopsL[(g * 64 + r) * 4];
                    const float4 cw = *(const float4*)&convwL[(g * 18 + q) * 4];
                    float a = cbL[c] + hv.x * cw.x + hv.y * cw.y + hv.z * cw.z + hv.w * cw.w;
                    float npv = (e == 0) ? npA.x : (e == 1) ? npA.y : (e == 2) ? npA.z : (e == 3) ? npA.w
                              : (e == 4) ? npB.x : (e == 5) ? npB.y : (e == 6) ? npB.z : npB.w;
                    val = silu_f(a) + npv;
                }
                unsigned int us = f2bf(val);
                if (e & 1) wd[e >> 1] |= (us << 16); else wd[e >> 1] |= us;
            }
            *(uint4*)&HtB[((c8 >> 3) * 64 + r) * 8] = make_uint4(wd[0], wd[1], wd[2], wd[3]);
        }
    }
    __syncthreads();

    // ---- stage 2: C1(64x64) = silu(H(64x128) @ Wm(128x64) + mb) -> C1B bf16
    {
        const int wr = w >> 1, wc = w & 1;
        float mb0 = mbL[wc * 32 + lm];
        float mb1 = mbL[wc * 32 + 16 + lm];
        f32x4 acc00 = {mb0, mb0, mb0, mb0};
        f32x4 acc01 = {mb1, mb1, mb1, mb1};
        f32x4 acc10 = {mb0, mb0, mb0, mb0};
        f32x4 acc11 = {mb1, mb1, mb1, mb1};
        #pragma unroll
        for (int kc = 0; kc < 4; ++kc) {
            const int kb = (kc * 4 + lg) * 64;
            bf16x8 a0 = *(const bf16x8*)&HtB[(kb + wr * 32 + lm) * 8];
            bf16x8 a1 = *(const bf16x8*)&HtB[(kb + wr * 32 + 16 + lm) * 8];
            bf16x8 b0 = *(const bf16x8*)&WmG[(kb + wc * 32 + lm) * 8];
            bf16x8 b1 = *(const bf16x8*)&WmG[(kb + wc * 32 + 16 + lm) * 8];
            acc00 = __builtin_amdgcn_mfma_f32_16x16x32_bf16(a0, b0, acc00, 0, 0, 0);
            acc01 = __builtin_amdgcn_mfma_f32_16x16x32_bf16(a0, b1, acc01, 0, 0, 0);
            acc10 = __builtin_amdgcn_mfma_f32_16x16x32_bf16(a1, b0, acc10, 0, 0, 0);
            acc11 = __builtin_amdgcn_mfma_f32_16x16x32_bf16(a1, b1, acc11, 0, 0, 0);
        }
        #pragma unroll
        for (int reg = 0; reg < 4; ++reg) {
            int row0 = wr * 32 + lg * 4 + reg;
            int col0 = wc * 32 + lm;
            C1B[((col0 >> 3) * 64 + row0) * 8 + (col0 & 7)] = f2bf(silu_f(acc00[reg]));
            int col1 = col0 + 16;
            C1B[((col1 >> 3) * 64 + row0) * 8 + (col1 & 7)] = f2bf(silu_f(acc01[reg]));
            int row1 = row0 + 16;
            C1B[((col0 >> 3) * 64 + row1) * 8 + (col0 & 7)] = f2bf(silu_f(acc10[reg]));
            C1B[((col1 >> 3) * 64 + row1) * 8 + (col1 & 7)] = f2bf(silu_f(acc11[reg]));
        }
    }
    __syncthreads();

    // ---- stage 3: C2(64x48) = C1(64x64) @ Ro(64x48) + rb ----
    {
        const int rt3 = w * 16;
        float r0 = rbL[lm], r1 = rbL[16 + lm], r2 = rbL[32 + lm];
        f32x4 c0 = {r0, r0, r0, r0};
        f32x4 c1 = {r1, r1, r1, r1};
        f32x4 c2 = {r2, r2, r2, r2};
        #pragma unroll
        for (int kc = 0; kc < 2; ++kc) {
            const int kb = kc * 4 + lg;
            bf16x8 a  = *(const bf16x8*)&C1B[(kb * 64 + rt3 + lm) * 8];
            bf16x8 b0 = *(const bf16x8*)&RoG[(kb * 48 + lm) * 8];
            bf16x8 b1 = *(const bf16x8*)&RoG[(kb * 48 + 16 + lm) * 8];
            bf16x8 b2 = *(const bf16x8*)&RoG[(kb * 48 + 32 + lm) * 8];
            c0 = __builtin_amdgcn_mfma_f32_16x16x32_bf16(a, b0, c0, 0, 0, 0);
            c1 = __builtin_amdgcn_mfma_f32_16x16x32_bf16(a, b1, c1, 0, 0, 0);
            c2 = __builtin_amdgcn_mfma_f32_16x16x32_bf16(a, b2, c2, 0, 0, 0);
        }
        float* C2L = (float*)HtB;   // HtB dead after stage 2
        #pragma unroll
        for (int reg = 0; reg < 4; ++reg) {
            int row = rt3 + lg * 4 + reg;
            C2L[row * 52 + lm]      = c0[reg];
            C2L[row * 52 + 16 + lm] = c1[reg];
            C2L[row * 52 + 32 + lm] = c2[reg];
        }
    }
    __syncthreads();

    // ---- output: out[b][hor][n][o] (plain cached stores: L2 merges lines) ----
    if (t < 192) {
        int b = t / 12, hor = t - b * 12;
        const float* C2L = (const float*)HtB;
        #pragma unroll
        for (int nl = 0; nl < 4; ++nl) {
            f32x4 v = *(const f32x4*)&C2L[(nl * 16 + b) * 52 + hor * 4];
            *(f32x4*)&out[(((size_t)b * 12 + hor) * 30000 + n0 + nl) * 4] = v;
        }
    }
}

// ---- launch --------------------------------------------------------------

extern "C" void kernel_launch(void* const* d_in, const int* in_sizes, int n_in,
                              void* d_out, int out_size, void* d_ws, size_t ws_size,
                              hipStream_t stream)
{
    const float* x      = (const float*)d_in[0];
    const int*   ei     = (const int*)d_in[1];
    const float* ew     = (const float*)d_in[2];
    const float* conv_w = (const float*)d_in[3];
    const float* conv_b = (const float*)d_in[4];
    const float* nemb   = (const float*)d_in[5];
    const float* emb_w  = (const float*)d_in[6];
    const float* emb_b  = (const float*)d_in[7];
    const float* mlp_w  = (const float*)d_in[8];
    const float* mlp_b  = (const float*)d_in[9];
    const float* ro_w   = (const float*)d_in[10];
    const float* ro_b   = (const float*)d_in[11];
    float* out = (float*)d_out;

    char* ws = (char*)d_ws;
    size_t off = 0;
    auto alloc = [&](size_t bytes) -> char* {
        char* p = ws + off;
        off += (bytes + 255) & ~(size_t)255;
        return p;
    };

    // zeroed region (must be first)
    int* cntF   = (int*)alloc(NN * 4);
    int* cntB   = (int*)alloc(NN * 4);
    int* curF   = (int*)alloc(NN * 4);
    int* curB   = (int*)alloc(NN * 4);
    size_t zeroBytes = off;

    int* rowF   = (int*)alloc((NN + 1) * 4);
    int* rowB   = (int*)alloc((NN + 1) * 4);
    int2* csrF  = (int2*)alloc((size_t)NE * 8);
    int2* csrB  = (int2*)alloc((size_t)NE * 8);
    float* xtF  = (float*)alloc((size_t)NN * 64 * 4);
    u16* xtB    = (u16*)alloc((size_t)NN * 64 * 2);
    u16* hbuf[6];
    for (int i = 0; i < 6; ++i) hbuf[i] = (u16*)alloc((size_t)NN * 64 * 2);
    u16* WmG    = (u16*)alloc(8192 * 2);
    u16* RoG    = (u16*)alloc(3072 * 2);
    float* cwT  = (float*)alloc(504 * 4);
    float* ewT  = (float*)alloc(4032 * 4);

    hipMemsetAsync(d_ws, 0, zeroBytes, stream);

    k_pack<<<4, 256, 0, stream>>>(mlp_w, ro_w, conv_w, emb_w, WmG, RoG, cwT, ewT);
    k_cnt<<<(NE + 255) / 256, 256, 0, stream>>>(ei, cntF, cntB);
    k_scan<<<2, 1024, 0, stream>>>(cntF, cntB, rowF, rowB);
    k_scatter<<<(NE + 255) / 256, 256, 0, stream>>>(ei, ew, rowF, rowB,
                                                    curF, curB, csrF, csrB);
    k_transpose<<<dim3((NN + 255) / 256, NB), 256, 0, stream>>>(x, xtF, xtB);

    dim3 hopGrid((NN + 3) / 4, 2);
    k_hop<<<hopGrid, 256, 0, stream>>>(xtB, hbuf[0], csrF, rowF,
                                       xtB, hbuf[3], csrB, rowB);
    k_hop<<<hopGrid, 256, 0, stream>>>(hbuf[0], hbuf[1], csrF, rowF,
                                       hbuf[3], hbuf[4], csrB, rowB);
    k_hop<<<hopGrid, 256, 0, stream>>>(hbuf[1], hbuf[2], csrF, rowF,
                                       hbuf[4], hbuf[5], csrB, rowB);

    k_fused<<<NN / 4, 256, 0, stream>>>(xtF, hbuf[0], hbuf[1], hbuf[2],
                                        hbuf[3], hbuf[4], hbuf[5],
                                        WmG, RoG, cwT, ewT, nemb,
                                        conv_b, emb_b, mlp_b, ro_b, out);
}